// Round 1
// baseline (392.849 us; speedup 1.0000x reference)
//
#include <hip/hip_runtime.h>

#define NB 64
#define NN 4096
#define ND 256
#define KK 1024

// ---------------- K1: logits[b,n] = dot(x[b,n,:], W) + bias, accumulated in f64.
// One wave (64 lanes) per row; lane l loads x[row, 4l..4l+3] as float4 (coalesced 1KB/row).
__global__ __launch_bounds__(256) void k_logits(const float* __restrict__ x,
                                                const float* __restrict__ W,
                                                const float* __restrict__ bias,
                                                double* __restrict__ logits) {
    const int wave = threadIdx.x >> 6;
    const int lane = threadIdx.x & 63;
    const long long row = (long long)blockIdx.x * 4 + wave;   // [0, NB*NN)
    const float4 xv = *reinterpret_cast<const float4*>(x + row * ND + lane * 4);
    const float4 wv = *reinterpret_cast<const float4*>(W + lane * 4);
    double acc = (double)xv.x * (double)wv.x + (double)xv.y * (double)wv.y
               + (double)xv.z * (double)wv.z + (double)xv.w * (double)wv.w;
    #pragma unroll
    for (int off = 32; off >= 1; off >>= 1)
        acc += __shfl_xor(acc, off, 64);
    if (lane == 0) logits[row] = acc + (double)bias[0];
}

// ---------------- K2: per-batch softmax stats + exact descending rank of every element.
// rank = ids_restore; rank<K -> kept. Value-binned radix rank: 4096 linear bins,
// LDS histogram + prefix scan + scatter, exact (logit, idx) compare within bin.
__global__ __launch_bounds__(1024) void k_rank(const double* __restrict__ logits,
                                               float* __restrict__ hard_mask,
                                               float* __restrict__ ids_restore,
                                               int* __restrict__ sel,
                                               float* __restrict__ sprob) {
    __shared__ double sl[NN];             // 32 KB: logits
    __shared__ unsigned int cnt[NN];      // 16 KB: histogram -> exclusive prefix
    __shared__ unsigned short sorted[NN]; //  8 KB: element ids grouped by bin
    __shared__ unsigned int tsum[1024];   //  4 KB: scan scratch
    __shared__ double dred[1024];         //  8 KB: reduce scratch
    __shared__ double s_max, s_min, s_sum;

    const int t = threadIdx.x;
    const int b = blockIdx.x;
    const double* lg = logits + (size_t)b * NN;

    double le[4];
    #pragma unroll
    for (int j = 0; j < 4; ++j) {
        const int e = t + j * 1024;
        le[j] = lg[e];
        sl[e] = le[j];
        cnt[e] = 0u;
    }
    double lmax = le[0], lmin = le[0];
    #pragma unroll
    for (int j = 1; j < 4; ++j) { lmax = fmax(lmax, le[j]); lmin = fmin(lmin, le[j]); }

    // block max
    dred[t] = lmax; __syncthreads();
    for (int off = 512; off > 0; off >>= 1) {
        if (t < off) dred[t] = fmax(dred[t], dred[t + off]);
        __syncthreads();
    }
    if (t == 0) s_max = dred[0];
    __syncthreads();
    // block min
    dred[t] = lmin; __syncthreads();
    for (int off = 512; off > 0; off >>= 1) {
        if (t < off) dred[t] = fmin(dred[t], dred[t + off]);
        __syncthreads();
    }
    if (t == 0) s_min = dred[0];
    __syncthreads();

    const double bmax = s_max;
    double ex_[4];
    double lsum = 0.0;
    #pragma unroll
    for (int j = 0; j < 4; ++j) { ex_[j] = exp(le[j] - bmax); lsum += ex_[j]; }
    dred[t] = lsum; __syncthreads();
    for (int off = 512; off > 0; off >>= 1) {
        if (t < off) dred[t] += dred[t + off];
        __syncthreads();
    }
    if (t == 0) s_sum = dred[0];
    __syncthreads();

    // histogram (bins: descending value -> ascending bin; monotone by floor())
    const double range = s_max - s_min;
    const double scale = (range > 0.0) ? (4095.0 / range) : 0.0;
    int bin_[4]; unsigned int off_[4];
    #pragma unroll
    for (int j = 0; j < 4; ++j) {
        int bn = (int)((s_max - le[j]) * scale);
        bn = min(max(bn, 0), NN - 1);
        bin_[j] = bn;
        off_[j] = atomicAdd(&cnt[bn], 1u);
    }
    __syncthreads();

    // exclusive prefix over 4096 bins (4 bins/thread + Hillis-Steele over 1024 partials)
    unsigned int c[4];
    #pragma unroll
    for (int j = 0; j < 4; ++j) c[j] = cnt[4 * t + j];
    const unsigned int s = c[0] + c[1] + c[2] + c[3];
    tsum[t] = s;
    __syncthreads();
    for (int off = 1; off < 1024; off <<= 1) {
        const unsigned int v = (t >= off) ? tsum[t - off] : 0u;
        __syncthreads();
        tsum[t] += v;
        __syncthreads();
    }
    unsigned int run = tsum[t] - s;   // exclusive across threads
    #pragma unroll
    for (int j = 0; j < 4; ++j) { cnt[4 * t + j] = run; run += c[j]; }
    __syncthreads();

    // scatter element ids grouped by bin
    #pragma unroll
    for (int j = 0; j < 4; ++j) {
        const int e = t + j * 1024;
        sorted[cnt[bin_[j]] + off_[j]] = (unsigned short)e;
    }
    __syncthreads();

    // exact rank: prefix[bin] + #(same-bin elements strictly preceding in (desc logit, asc idx))
    const double inv_sum = 1.0 / s_sum;
    #pragma unroll
    for (int j = 0; j < 4; ++j) {
        const int e = t + j * 1024;
        const double myl = le[j];
        const int bn = bin_[j];
        const unsigned int base = cnt[bn];
        const unsigned int end = (bn < NN - 1) ? cnt[bn + 1] : (unsigned int)NN;
        unsigned int r = base;
        for (unsigned int m = base; m < end; ++m) {
            const int o = sorted[m];
            const double lo_ = sl[o];
            if (lo_ > myl || (lo_ == myl && o < e)) r++;
        }
        const float pr = (float)(ex_[j] * inv_sum);
        const size_t gi = (size_t)b * NN + e;
        hard_mask[gi] = (r < KK) ? 0.0f : 1.0f;
        ids_restore[gi] = (float)r;
        if (r < KK) { sel[b * KK + r] = e; sprob[b * KK + r] = pr; }
    }
}

// ---------------- K3: x_masked[b,r,:] = x[b, sel[b,r], :] * sprob[b,r]. One wave per row.
__global__ __launch_bounds__(256) void k_gather(const float* __restrict__ x,
                                                const int* __restrict__ sel,
                                                const float* __restrict__ sprob,
                                                float* __restrict__ xm) {
    const int wave = threadIdx.x >> 6;
    const int lane = threadIdx.x & 63;
    const int row = blockIdx.x * 4 + wave;     // [0, NB*KK)
    const int b = row >> 10;
    const int n = sel[row];
    const float p = sprob[row];
    const float4 xv = *reinterpret_cast<const float4*>(x + ((size_t)b * NN + n) * ND + lane * 4);
    float4 o;
    o.x = xv.x * p; o.y = xv.y * p; o.z = xv.z * p; o.w = xv.w * p;
    *reinterpret_cast<float4*>(xm + (size_t)row * ND + lane * 4) = o;
}

extern "C" void kernel_launch(void* const* d_in, const int* in_sizes, int n_in,
                              void* d_out, int out_size, void* d_ws, size_t ws_size,
                              hipStream_t stream) {
    const float* x    = (const float*)d_in[0];
    const float* W    = (const float*)d_in[1];
    const float* bias = (const float*)d_in[2];
    // d_in[3] is K == 1024 (hardcoded)

    float* out         = (float*)d_out;
    float* x_masked    = out;                                   // NB*KK*ND
    float* hard_mask   = out + (size_t)NB * KK * ND;            // NB*NN
    float* ids_restore = hard_mask + (size_t)NB * NN;           // NB*NN

    double* logits = (double*)d_ws;                             // NB*NN doubles (2 MB)
    int*    sel    = (int*)(logits + (size_t)NB * NN);          // NB*KK ints
    float*  sprob  = (float*)(sel + (size_t)NB * KK);           // NB*KK floats

    hipLaunchKernelGGL(k_logits, dim3(NB * NN / 4), dim3(256), 0, stream, x, W, bias, logits);
    hipLaunchKernelGGL(k_rank,   dim3(NB),          dim3(1024), 0, stream, logits, hard_mask,
                       ids_restore, sel, sprob);
    hipLaunchKernelGGL(k_gather, dim3(NB * KK / 4), dim3(256), 0, stream, x, sel, sprob, x_masked);
}

// Round 2
// 390.150 us; speedup vs baseline: 1.0069x; 1.0069x over previous
//
#include <hip/hip_runtime.h>

#define NB 64
#define NN 4096
#define ND 256
#define KK 1024

// ---------------- K1: logits[b,n] = dot(x[b,n,:], W) + bias, accumulated in f64.
// One wave (64 lanes) per row; lane l loads x[row, 4l..4l+3] as float4 (coalesced 1KB/row).
__global__ __launch_bounds__(256) void k_logits(const float* __restrict__ x,
                                                const float* __restrict__ W,
                                                const float* __restrict__ bias,
                                                double* __restrict__ logits) {
    const int wave = threadIdx.x >> 6;
    const int lane = threadIdx.x & 63;
    const long long row = (long long)blockIdx.x * 4 + wave;   // [0, NB*NN)
    const float4 xv = *reinterpret_cast<const float4*>(x + row * ND + lane * 4);
    const float4 wv = *reinterpret_cast<const float4*>(W + lane * 4);
    double acc = (double)xv.x * (double)wv.x + (double)xv.y * (double)wv.y
               + (double)xv.z * (double)wv.z + (double)xv.w * (double)wv.w;
    #pragma unroll
    for (int off = 32; off >= 1; off >>= 1)
        acc += __shfl_xor(acc, off, 64);
    if (lane == 0) logits[row] = acc + (double)bias[0];
}

// ---------------- K2: per-batch softmax + exact descending rank (value-binned radix rank).
// Rewritten with wave-level shuffle reductions/scans: ~8 barriers instead of ~56.
__global__ __launch_bounds__(1024) void k_rank(const double* __restrict__ logits,
                                               float* __restrict__ hard_mask,
                                               float* __restrict__ ids_restore,
                                               int* __restrict__ sel,
                                               float* __restrict__ sprob) {
    __shared__ double sl[NN];             // 32 KB: logits
    __shared__ unsigned int cnt[NN];      // 16 KB: histogram -> exclusive prefix
    __shared__ unsigned short sorted[NN]; //  8 KB: element ids grouped by bin
    __shared__ double wmax[16], wmin[16], wsum[16];
    __shared__ unsigned int wscan[16];
    __shared__ double s_max, s_min, s_sum;

    const int t = threadIdx.x;
    const int wid = t >> 6;
    const int lane = t & 63;
    const int b = blockIdx.x;
    const double* lg = logits + (size_t)b * NN;

    double le[4];
    #pragma unroll
    for (int j = 0; j < 4; ++j) {
        const int e = t + j * 1024;
        le[j] = lg[e];
        sl[e] = le[j];
        cnt[e] = 0u;
    }
    double lmax = le[0], lmin = le[0];
    #pragma unroll
    for (int j = 1; j < 4; ++j) { lmax = fmax(lmax, le[j]); lmin = fmin(lmin, le[j]); }

    // wave-level max/min (no barriers), then 16 partials reduced by waves 0 and 1
    #pragma unroll
    for (int off = 32; off >= 1; off >>= 1) {
        lmax = fmax(lmax, __shfl_xor(lmax, off, 64));
        lmin = fmin(lmin, __shfl_xor(lmin, off, 64));
    }
    if (lane == 0) { wmax[wid] = lmax; wmin[wid] = lmin; }
    __syncthreads();
    if (t < 16) {
        double m = wmax[t];
        #pragma unroll
        for (int off = 8; off >= 1; off >>= 1) m = fmax(m, __shfl_xor(m, off, 16));
        if (t == 0) s_max = m;
    } else if (t >= 64 && t < 80) {
        double m = wmin[t - 64];
        #pragma unroll
        for (int off = 8; off >= 1; off >>= 1) m = fmin(m, __shfl_xor(m, off, 16));
        if (t == 64) s_min = m;
    }
    __syncthreads();

    const double bmax = s_max;
    double ex_[4];
    double lsum = 0.0;
    #pragma unroll
    for (int j = 0; j < 4; ++j) { ex_[j] = exp(le[j] - bmax); lsum += ex_[j]; }
    #pragma unroll
    for (int off = 32; off >= 1; off >>= 1) lsum += __shfl_xor(lsum, off, 64);
    if (lane == 0) wsum[wid] = lsum;
    __syncthreads();
    if (t < 16) {
        double m = wsum[t];
        #pragma unroll
        for (int off = 8; off >= 1; off >>= 1) m += __shfl_xor(m, off, 16);
        if (t == 0) s_sum = m;
    }
    __syncthreads();

    // histogram (bins: descending value -> ascending bin; monotone by floor())
    const double range = s_max - s_min;
    const double scale = (range > 0.0) ? (4095.0 / range) : 0.0;
    int bin_[4]; unsigned int off_[4];
    #pragma unroll
    for (int j = 0; j < 4; ++j) {
        int bn = (int)((s_max - le[j]) * scale);
        bn = min(max(bn, 0), NN - 1);
        bin_[j] = bn;
        off_[j] = atomicAdd(&cnt[bn], 1u);
    }
    __syncthreads();

    // exclusive prefix over 4096 bins: 4 bins/thread, wave-shuffle scan + cross-wave stage
    unsigned int c[4];
    #pragma unroll
    for (int j = 0; j < 4; ++j) c[j] = cnt[4 * t + j];
    const unsigned int s = c[0] + c[1] + c[2] + c[3];
    unsigned int v = s;                       // wave-inclusive scan of s
    #pragma unroll
    for (int off = 1; off < 64; off <<= 1) {
        const unsigned int u = __shfl_up(v, off, 64);
        if (lane >= off) v += u;
    }
    if (lane == 63) wscan[wid] = v;
    __syncthreads();
    if (t < 16) {
        unsigned int u = wscan[t];
        #pragma unroll
        for (int off = 1; off < 16; off <<= 1) {
            const unsigned int w2 = __shfl_up(u, off, 16);
            if (t >= off) u += w2;
        }
        wscan[t] = u;                         // inclusive wave totals
    }
    __syncthreads();
    unsigned int run = v - s + (wid ? wscan[wid - 1] : 0u);   // exclusive across all threads
    #pragma unroll
    for (int j = 0; j < 4; ++j) { cnt[4 * t + j] = run; run += c[j]; }
    __syncthreads();

    // scatter element ids grouped by bin
    #pragma unroll
    for (int j = 0; j < 4; ++j) {
        const int e = t + j * 1024;
        sorted[cnt[bin_[j]] + off_[j]] = (unsigned short)e;
    }
    __syncthreads();

    // exact rank: prefix[bin] + #(same-bin elements strictly preceding in (desc logit, asc idx))
    const double inv_sum = 1.0 / s_sum;
    #pragma unroll
    for (int j = 0; j < 4; ++j) {
        const int e = t + j * 1024;
        const double myl = le[j];
        const int bn = bin_[j];
        const unsigned int base = cnt[bn];
        const unsigned int end = (bn < NN - 1) ? cnt[bn + 1] : (unsigned int)NN;
        unsigned int r = base;
        for (unsigned int m = base; m < end; ++m) {
            const int o = sorted[m];
            const double lo_ = sl[o];
            if (lo_ > myl || (lo_ == myl && o < e)) r++;
        }
        const float pr = (float)(ex_[j] * inv_sum);
        const size_t gi = (size_t)b * NN + e;
        hard_mask[gi] = (r < KK) ? 0.0f : 1.0f;
        ids_restore[gi] = (float)r;
        if (r < KK) { sel[b * KK + r] = e; sprob[b * KK + r] = pr; }
    }
}

// ---------------- K3: x_masked[b,r,:] = x[b, sel[b,r], :] * sprob[b,r]. One wave per row.
__global__ __launch_bounds__(256) void k_gather(const float* __restrict__ x,
                                                const int* __restrict__ sel,
                                                const float* __restrict__ sprob,
                                                float* __restrict__ xm) {
    const int wave = threadIdx.x >> 6;
    const int lane = threadIdx.x & 63;
    const int row = blockIdx.x * 4 + wave;     // [0, NB*KK)
    const int b = row >> 10;
    const int n = sel[row];
    const float p = sprob[row];
    const float4 xv = *reinterpret_cast<const float4*>(x + ((size_t)b * NN + n) * ND + lane * 4);
    float4 o;
    o.x = xv.x * p; o.y = xv.y * p; o.z = xv.z * p; o.w = xv.w * p;
    *reinterpret_cast<float4*>(xm + (size_t)row * ND + lane * 4) = o;
}

extern "C" void kernel_launch(void* const* d_in, const int* in_sizes, int n_in,
                              void* d_out, int out_size, void* d_ws, size_t ws_size,
                              hipStream_t stream) {
    const float* x    = (const float*)d_in[0];
    const float* W    = (const float*)d_in[1];
    const float* bias = (const float*)d_in[2];
    // d_in[3] is K == 1024 (hardcoded)

    float* out         = (float*)d_out;
    float* x_masked    = out;                                   // NB*KK*ND
    float* hard_mask   = out + (size_t)NB * KK * ND;            // NB*NN
    float* ids_restore = hard_mask + (size_t)NB * NN;           // NB*NN

    double* logits = (double*)d_ws;                             // NB*NN doubles (2 MB)
    int*    sel    = (int*)(logits + (size_t)NB * NN);          // NB*KK ints
    float*  sprob  = (float*)(sel + (size_t)NB * KK);           // NB*KK floats

    hipLaunchKernelGGL(k_logits, dim3(NB * NN / 4), dim3(256), 0, stream, x, W, bias, logits);
    hipLaunchKernelGGL(k_rank,   dim3(NB),          dim3(1024), 0, stream, logits, hard_mask,
                       ids_restore, sel, sprob);
    hipLaunchKernelGGL(k_gather, dim3(NB * KK / 4), dim3(256), 0, stream, x, sel, sprob, x_masked);
}